// Round 6
// baseline (292.645 us; speedup 1.0000x reference)
//
#include <hip/hip_runtime.h>

// Problem dims (fixed by reference setup_inputs)
constexpr int B = 64, T = 256, I = 2048, H = 4096, O = 1024;

#define DECAY 0.9f
#define THRESH 1.0f

typedef __attribute__((ext_vector_type(8))) __bf16 bf16x8;
typedef __attribute__((ext_vector_type(4))) float f32x4;

// ---------------------------------------------------------------------------
// fp32 -> (hi, lo) bf16 split by truncation. a ~= hi + lo with |err| <~ 2^-16 |a|
// ---------------------------------------------------------------------------
__device__ inline void split_bf16(float a, unsigned short& hi, unsigned short& lo) {
    unsigned int u = __float_as_uint(a);
    hi = (unsigned short)(u >> 16);
    float fhi = __uint_as_float(u & 0xffff0000u);
    lo = (unsigned short)(__float_as_uint(a - fhi) >> 16);
}

// ---------------------------------------------------------------------------
// Kernel 1a: partial batch sums, 4 b-groups of 16 -> 2048 blocks (8/CU).
// x read = 134 MB: the HBM floor of the whole problem.
// ---------------------------------------------------------------------------
__global__ __launch_bounds__(256) void batch_reduce_part(const float* __restrict__ x,
                                                         float* __restrict__ brp) {
    const int idx = blockIdx.x * 256 + threadIdx.x;   // float4 index in [T*I/4)
    const int zb = blockIdx.y;                        // 0..3
    const int plane4 = (T * I) / 4;
    const float4* x4 = (const float4*)x + (size_t)zb * 16 * plane4;
    float4 acc = {0.f, 0.f, 0.f, 0.f};
#pragma unroll 16
    for (int b = 0; b < 16; ++b) {
        float4 v = x4[idx + (size_t)b * plane4];
        acc.x += v.x; acc.y += v.y; acc.z += v.z; acc.w += v.w;
    }
    ((float4*)brp)[(size_t)zb * plane4 + idx] = acc;
}

// ---------------------------------------------------------------------------
// Kernel 1b: combine 4 partial planes, scale by 1/B, emit bf16 hi/lo planes.
// 16 MB read + 4 MB write: ~3 us.
// ---------------------------------------------------------------------------
__global__ __launch_bounds__(256) void batch_combine(const float* __restrict__ brp,
                                                     unsigned short* __restrict__ xh,
                                                     unsigned short* __restrict__ xl) {
    const int idx = blockIdx.x * 256 + threadIdx.x;   // float4 index
    const int plane4 = (T * I) / 4;
    float4 p0 = ((const float4*)brp)[idx];
    float4 p1 = ((const float4*)brp)[(size_t)plane4 + idx];
    float4 p2 = ((const float4*)brp)[(size_t)2 * plane4 + idx];
    float4 p3 = ((const float4*)brp)[(size_t)3 * plane4 + idx];
    const float s = 1.0f / (float)B;
    float a[4] = {(p0.x + p1.x + p2.x + p3.x) * s, (p0.y + p1.y + p2.y + p3.y) * s,
                  (p0.z + p1.z + p2.z + p3.z) * s, (p0.w + p1.w + p2.w + p3.w) * s};
    unsigned short hi[4], lo[4];
#pragma unroll
    for (int j = 0; j < 4; ++j) split_bf16(a[j], hi[j], lo[j]);
    uint2 ph, pl;
    ph.x = (unsigned int)hi[0] | ((unsigned int)hi[1] << 16);
    ph.y = (unsigned int)hi[2] | ((unsigned int)hi[3] << 16);
    pl.x = (unsigned int)lo[0] | ((unsigned int)lo[1] << 16);
    pl.y = (unsigned int)lo[2] | ((unsigned int)lo[3] << 16);
    ((uint2*)xh)[idx] = ph;
    ((uint2*)xl)[idx] = pl;
}

// ---------------------------------------------------------------------------
// Kernel 2 (fallback path only): currents[t,h] = b_in[h]
// ---------------------------------------------------------------------------
__global__ __launch_bounds__(256) void cur_init(const float* __restrict__ b_in,
                                                float* __restrict__ cur) {
    const int idx = blockIdx.x * 256 + threadIdx.x;
    const int h4 = idx & (H / 4 - 1);
    ((float4*)cur)[idx] = ((const float4*)b_in)[h4];
}

// ---------------------------------------------------------------------------
// Kernel 3: currents += xbar @ W_in  via bf16 hi/lo 3-pass MFMA (fp32-accurate)
// BM=256(=T: W_in read exactly once), BN=32, BK=32, KSPLIT=4 -> 512 blocks.
// Non-pipelined (round-5 A/B showed explicit pipelining is neutral here; the
// 2 blocks/CU wave-level overlap already hides the staging latency).
// ---------------------------------------------------------------------------
#define BN 32
#define BK 32
#define KSPLIT 4
#define KCHUNK (I / KSPLIT)  // 512

__global__ __launch_bounds__(256) void gemm_in(const unsigned short* __restrict__ xh,
                                               const unsigned short* __restrict__ xl,
                                               const float* __restrict__ Wi,   // [I,H]
                                               float* __restrict__ dst,
                                               int useAtomic) {
    __shared__ unsigned short BtH[BN][BK + 8];  // [n][k], row stride 40 (80 B)
    __shared__ unsigned short BtL[BN][BK + 8];

    const int tid = threadIdx.x;
    const int n0 = blockIdx.x * BN;
    const int split = blockIdx.y;
    const int kBeg = split * KCHUNK;
    const int wave = tid >> 6, lane = tid & 63;
    const int quad = lane >> 4, l16 = lane & 15;
    const int m0 = wave * 64;  // each wave owns a 64-row m-strip (4 m-tiles)

    const int sn = tid & 31;          // staging: n within tile
    const int sk = (tid >> 5) << 2;   // staging: k base (0,4,...,28)

    f32x4 acc[4][2];
#pragma unroll
    for (int mi = 0; mi < 4; ++mi)
#pragma unroll
        for (int ni = 0; ni < 2; ++ni) acc[mi][ni] = (f32x4){0.f, 0.f, 0.f, 0.f};

    for (int k0 = kBeg; k0 < kBeg + KCHUNK; k0 += BK) {
        // --- global loads (issued before barrier; overlap with prev compute) ---
        const float* src = &Wi[(size_t)(k0 + sk) * H + n0 + sn];
        float v0 = src[0], v1 = src[(size_t)H], v2 = src[(size_t)2 * H], v3 = src[(size_t)3 * H];

        bf16x8 aH[4], aL[4];
#pragma unroll
        for (int mi = 0; mi < 4; ++mi) {
            const size_t arow = (size_t)(m0 + mi * 16 + l16) * I + k0 + quad * 8;
            aH[mi] = *(const bf16x8*)(xh + arow);
            aL[mi] = *(const bf16x8*)(xl + arow);
        }

        unsigned short h0, h1, h2, h3, l0, l1, l2, l3;
        split_bf16(v0, h0, l0); split_bf16(v1, h1, l1);
        split_bf16(v2, h2, l2); split_bf16(v3, h3, l3);

        __syncthreads();  // previous iteration's LDS readers done
        uint2 ph, pl;
        ph.x = (unsigned int)h0 | ((unsigned int)h1 << 16);
        ph.y = (unsigned int)h2 | ((unsigned int)h3 << 16);
        pl.x = (unsigned int)l0 | ((unsigned int)l1 << 16);
        pl.y = (unsigned int)l2 | ((unsigned int)l3 << 16);
        *(uint2*)&BtH[sn][sk] = ph;
        *(uint2*)&BtL[sn][sk] = pl;
        __syncthreads();

        bf16x8 bH[2], bL[2];
#pragma unroll
        for (int ni = 0; ni < 2; ++ni) {
            bH[ni] = *(const bf16x8*)&BtH[ni * 16 + l16][quad * 8];
            bL[ni] = *(const bf16x8*)&BtL[ni * 16 + l16][quad * 8];
        }
#pragma unroll
        for (int mi = 0; mi < 4; ++mi)
#pragma unroll
            for (int ni = 0; ni < 2; ++ni) {
                acc[mi][ni] = __builtin_amdgcn_mfma_f32_16x16x32_bf16(aL[mi], bH[ni], acc[mi][ni], 0, 0, 0);
                acc[mi][ni] = __builtin_amdgcn_mfma_f32_16x16x32_bf16(aH[mi], bL[ni], acc[mi][ni], 0, 0, 0);
                acc[mi][ni] = __builtin_amdgcn_mfma_f32_16x16x32_bf16(aH[mi], bH[ni], acc[mi][ni], 0, 0, 0);
            }
    }

    // epilogue: C/D layout col=lane&15, row=quad*4+reg (verified m89/m91)
    float* base = useAtomic ? dst : dst + (size_t)split * T * H;
#pragma unroll
    for (int mi = 0; mi < 4; ++mi)
#pragma unroll
        for (int ni = 0; ni < 2; ++ni) {
            const int h = n0 + ni * 16 + l16;
#pragma unroll
            for (int r = 0; r < 4; ++r) {
                const int m = m0 + mi * 16 + quad * 4 + r;
                if (useAtomic) atomicAdd(&base[(size_t)m * H + h], acc[mi][ni][r]);
                else           base[(size_t)m * H + h] = acc[mi][ni][r];
            }
        }
}

// ---------------------------------------------------------------------------
// Kernel 4: FUSED split-K fold + bias + LIF scan + d_out bias-init.
// One thread per h. Per 8-t batch, loads all NS plane values (8*NS loads in
// flight), double-buffered against the dependent LIF chain. Compile-time NS.
// Blocks 0..O/64-1 also write out = b_out (out_gemv atomics come after).
// ---------------------------------------------------------------------------
template <int NS>
__global__ __launch_bounds__(64) void lif_scan(const float* __restrict__ part, // [NS][T][H]
                                               const float* __restrict__ b_in, // may be null
                                               const float* __restrict__ m0v,  // [H]
                                               const float* __restrict__ b_out,// [O]
                                               float* __restrict__ agg,        // [H]
                                               float* __restrict__ out) {      // [O]
    const int h = blockIdx.x * 64 + threadIdx.x;
    const float bias = b_in ? b_in[h] : 0.f;
    float m = m0v[h];
    float cnt = 0.f;
    constexpr int D = 8;       // t-depth per batch
    float buf[2][D * NS];
#pragma unroll
    for (int j = 0; j < D; ++j)
#pragma unroll
        for (int s = 0; s < NS; ++s)
            buf[0][j * NS + s] = part[((size_t)s * T + j) * H + h];
#pragma unroll
    for (int b = 0; b < T / D; ++b) {
        const int cur = b & 1;
        if (b + 1 < T / D) {
#pragma unroll
            for (int j = 0; j < D; ++j)
#pragma unroll
                for (int s = 0; s < NS; ++s)
                    buf[cur ^ 1][j * NS + s] = part[((size_t)s * T + (b + 1) * D + j) * H + h];
        }
#pragma unroll
        for (int j = 0; j < D; ++j) {
            float c = bias;
#pragma unroll
            for (int s = 0; s < NS; ++s) c += buf[cur][j * NS + s];
            m = DECAY * m + c;
            if (m > THRESH) { cnt += 1.f; m = 0.f; }
        }
    }
    agg[h] = cnt * (1.0f / (float)T);
    if (blockIdx.x < O / 64) {
        const int o = blockIdx.x * 64 + threadIdx.x;
        out[o] = b_out[o];
    }
}

// ---------------------------------------------------------------------------
// Kernel 5: out += agg @ W_out  (out pre-set to b_out by lif_scan)
// ---------------------------------------------------------------------------
__global__ __launch_bounds__(256) void out_gemv(const float* __restrict__ agg,
                                                const float* __restrict__ Wout,  // [H,O]
                                                float* __restrict__ out) {
    const int o = blockIdx.x * 256 + threadIdx.x;
    const int h0 = blockIdx.y * 64;
    float s = 0.f;
#pragma unroll 8
    for (int hh = h0; hh < h0 + 64; ++hh) {
        s += agg[hh] * Wout[(size_t)hh * O + o];
    }
    atomicAdd(&out[o], s);
}

// ---------------------------------------------------------------------------
extern "C" void kernel_launch(void* const* d_in, const int* in_sizes, int n_in,
                              void* d_out, int out_size, void* d_ws, size_t ws_size,
                              hipStream_t stream) {
    const float* x     = (const float*)d_in[0];
    const float* W_in  = (const float*)d_in[1];
    const float* b_in  = (const float*)d_in[2];
    const float* W_out = (const float*)d_in[3];
    const float* b_out = (const float*)d_in[4];
    const float* m0    = (const float*)d_in[5];
    float* out = (float*)d_out;

    // ws: xbar_hi [T*I u16] | xbar_lo [T*I u16] | agg [H f32]
    //     | part [KSPLIT*T*H f32] | brp [4*T*I f32]      (~29.2 MB total)
    unsigned short* xh = (unsigned short*)d_ws;
    unsigned short* xl = xh + (size_t)T * I;
    float* agg  = (float*)(xl + (size_t)T * I);
    float* part = agg + H;
    float* brp  = part + (size_t)KSPLIT * T * H;

    const size_t need = (size_t)2 * T * I * 2 + (size_t)H * 4
                      + (size_t)KSPLIT * T * H * 4 + (size_t)4 * T * I * 4;
    const int fits = (ws_size >= need) ? 1 : 0;  // ws_size constant -> same path every launch

    // 1) batch mean: 4 b-quarters (2048 blocks) then combine to bf16 hi/lo
    dim3 g1((T * I / 4) / 256, 4);
    batch_reduce_part<<<g1, 256, 0, stream>>>(x, brp);
    batch_combine<<<(T * I / 4) / 256, 256, 0, stream>>>(brp, xh, xl);

    dim3 g2(H / BN, KSPLIT);
    if (fits) {
        // 2) MFMA GEMM into split-K partial planes (plain stores)
        gemm_in<<<g2, 256, 0, stream>>>(xh, xl, W_in, part, 0);
        // 3) fused fold+bias+LIF (+ out=b_out init)
        lif_scan<KSPLIT><<<H / 64, 64, 0, stream>>>(part, b_in, m0, b_out, agg, out);
    } else {
        // fallback (small ws): atomic accumulation into a single bias-primed plane
        cur_init<<<(T * H / 4) / 256, 256, 0, stream>>>(b_in, part);
        gemm_in<<<g2, 256, 0, stream>>>(xh, xl, W_in, part, 1);
        lif_scan<1><<<H / 64, 64, 0, stream>>>(part, nullptr, m0, b_out, agg, out);
    }

    // 4) out += agg @ W_out
    dim3 g4(O / 256, H / 64);
    out_gemv<<<g4, 256, 0, stream>>>(agg, W_out, out);
}

// Round 7
// 279.157 us; speedup vs baseline: 1.0483x; 1.0483x over previous
//
#include <hip/hip_runtime.h>

// Problem dims (fixed by reference setup_inputs)
constexpr int B = 64, T = 256, I = 2048, H = 4096, O = 1024;

#define DECAY 0.9f
#define THRESH 1.0f

typedef __attribute__((ext_vector_type(8))) __bf16 bf16x8;
typedef __attribute__((ext_vector_type(4))) float f32x4;

// ---------------------------------------------------------------------------
// fp32 -> (hi, lo) bf16 split by truncation. a ~= hi + lo with |err| <~ 2^-16 |a|
// ---------------------------------------------------------------------------
__device__ inline void split_bf16(float a, unsigned short& hi, unsigned short& lo) {
    unsigned int u = __float_as_uint(a);
    hi = (unsigned short)(u >> 16);
    float fhi = __uint_as_float(u & 0xffff0000u);
    lo = (unsigned short)(__float_as_uint(a - fhi) >> 16);
}

// ---------------------------------------------------------------------------
// Kernel 1: xbar = (1/B) sum_b x[b]  -> write bf16 hi/lo planes [T,I]
// 134 MB read: the HBM floor of the whole problem (~21 us @ 6.3 TB/s).
// (A/B across rounds: 2-way/4-way b-splits were neutral-to-negative; the
//  single 64-deep unroll-16 form is the round-4 best. Keep it.)
// ---------------------------------------------------------------------------
__global__ __launch_bounds__(256) void batch_reduce(const float* __restrict__ x,
                                                    unsigned short* __restrict__ xh,
                                                    unsigned short* __restrict__ xl) {
    const int idx = blockIdx.x * 256 + threadIdx.x;  // float4 index in [T*I/4)
    const float4* x4 = (const float4*)x;
    const int stride4 = (T * I) / 4;
    float4 acc = {0.f, 0.f, 0.f, 0.f};
#pragma unroll 16
    for (int b = 0; b < B; ++b) {
        float4 v = x4[idx + (size_t)b * stride4];
        acc.x += v.x; acc.y += v.y; acc.z += v.z; acc.w += v.w;
    }
    const float s = 1.0f / (float)B;
    float a[4] = {acc.x * s, acc.y * s, acc.z * s, acc.w * s};
    unsigned short hi[4], lo[4];
#pragma unroll
    for (int j = 0; j < 4; ++j) split_bf16(a[j], hi[j], lo[j]);
    uint2 ph, pl;
    ph.x = (unsigned int)hi[0] | ((unsigned int)hi[1] << 16);
    ph.y = (unsigned int)hi[2] | ((unsigned int)hi[3] << 16);
    pl.x = (unsigned int)lo[0] | ((unsigned int)lo[1] << 16);
    pl.y = (unsigned int)lo[2] | ((unsigned int)lo[3] << 16);
    ((uint2*)xh)[idx] = ph;
    ((uint2*)xl)[idx] = pl;
}

// ---------------------------------------------------------------------------
// Kernel 2 (fallback path only): currents[t,h] = b_in[h]
// ---------------------------------------------------------------------------
__global__ __launch_bounds__(256) void cur_init(const float* __restrict__ b_in,
                                                float* __restrict__ cur) {
    const int idx = blockIdx.x * 256 + threadIdx.x;
    const int h4 = idx & (H / 4 - 1);
    ((float4*)cur)[idx] = ((const float4*)b_in)[h4];
}

// ---------------------------------------------------------------------------
// Kernel 3: currents += xbar @ W_in  via bf16 hi/lo 3-pass MFMA (fp32-accurate)
// BM=256(=T: W_in read exactly once), BN=32, BK=32, KSPLIT=4 -> 512 blocks.
// Non-pipelined (round-5 A/B: explicit pipelining neutral; 2 blocks/CU
// wave-level overlap already hides staging latency).
// ---------------------------------------------------------------------------
#define BN 32
#define BK 32
#define KSPLIT 4
#define KCHUNK (I / KSPLIT)  // 512

__global__ __launch_bounds__(256) void gemm_in(const unsigned short* __restrict__ xh,
                                               const unsigned short* __restrict__ xl,
                                               const float* __restrict__ Wi,   // [I,H]
                                               float* __restrict__ dst,
                                               int useAtomic) {
    __shared__ unsigned short BtH[BN][BK + 8];  // [n][k], row stride 40 (80 B)
    __shared__ unsigned short BtL[BN][BK + 8];

    const int tid = threadIdx.x;
    const int n0 = blockIdx.x * BN;
    const int split = blockIdx.y;
    const int kBeg = split * KCHUNK;
    const int wave = tid >> 6, lane = tid & 63;
    const int quad = lane >> 4, l16 = lane & 15;
    const int m0 = wave * 64;  // each wave owns a 64-row m-strip (4 m-tiles)

    const int sn = tid & 31;          // staging: n within tile
    const int sk = (tid >> 5) << 2;   // staging: k base (0,4,...,28)

    f32x4 acc[4][2];
#pragma unroll
    for (int mi = 0; mi < 4; ++mi)
#pragma unroll
        for (int ni = 0; ni < 2; ++ni) acc[mi][ni] = (f32x4){0.f, 0.f, 0.f, 0.f};

    for (int k0 = kBeg; k0 < kBeg + KCHUNK; k0 += BK) {
        // --- global loads (issued before barrier; overlap with prev compute) ---
        const float* src = &Wi[(size_t)(k0 + sk) * H + n0 + sn];
        float v0 = src[0], v1 = src[(size_t)H], v2 = src[(size_t)2 * H], v3 = src[(size_t)3 * H];

        bf16x8 aH[4], aL[4];
#pragma unroll
        for (int mi = 0; mi < 4; ++mi) {
            const size_t arow = (size_t)(m0 + mi * 16 + l16) * I + k0 + quad * 8;
            aH[mi] = *(const bf16x8*)(xh + arow);
            aL[mi] = *(const bf16x8*)(xl + arow);
        }

        unsigned short h0, h1, h2, h3, l0, l1, l2, l3;
        split_bf16(v0, h0, l0); split_bf16(v1, h1, l1);
        split_bf16(v2, h2, l2); split_bf16(v3, h3, l3);

        __syncthreads();  // previous iteration's LDS readers done
        uint2 ph, pl;
        ph.x = (unsigned int)h0 | ((unsigned int)h1 << 16);
        ph.y = (unsigned int)h2 | ((unsigned int)h3 << 16);
        pl.x = (unsigned int)l0 | ((unsigned int)l1 << 16);
        pl.y = (unsigned int)l2 | ((unsigned int)l3 << 16);
        *(uint2*)&BtH[sn][sk] = ph;
        *(uint2*)&BtL[sn][sk] = pl;
        __syncthreads();

        bf16x8 bH[2], bL[2];
#pragma unroll
        for (int ni = 0; ni < 2; ++ni) {
            bH[ni] = *(const bf16x8*)&BtH[ni * 16 + l16][quad * 8];
            bL[ni] = *(const bf16x8*)&BtL[ni * 16 + l16][quad * 8];
        }
#pragma unroll
        for (int mi = 0; mi < 4; ++mi)
#pragma unroll
            for (int ni = 0; ni < 2; ++ni) {
                acc[mi][ni] = __builtin_amdgcn_mfma_f32_16x16x32_bf16(aL[mi], bH[ni], acc[mi][ni], 0, 0, 0);
                acc[mi][ni] = __builtin_amdgcn_mfma_f32_16x16x32_bf16(aH[mi], bL[ni], acc[mi][ni], 0, 0, 0);
                acc[mi][ni] = __builtin_amdgcn_mfma_f32_16x16x32_bf16(aH[mi], bH[ni], acc[mi][ni], 0, 0, 0);
            }
    }

    // epilogue: C/D layout col=lane&15, row=quad*4+reg (verified m89/m91)
    float* base = useAtomic ? dst : dst + (size_t)split * T * H;
#pragma unroll
    for (int mi = 0; mi < 4; ++mi)
#pragma unroll
        for (int ni = 0; ni < 2; ++ni) {
            const int h = n0 + ni * 16 + l16;
#pragma unroll
            for (int r = 0; r < 4; ++r) {
                const int m = m0 + mi * 16 + quad * 4 + r;
                if (useAtomic) atomicAdd(&base[(size_t)m * H + h], acc[mi][ni][r]);
                else           base[(size_t)m * H + h] = acc[mi][ni][r];
            }
        }
}

// ---------------------------------------------------------------------------
// Kernel 4: fold split-K partials + bias into plane 0 IN-PLACE (1024 blocks,
// full-BW kernel — all bulk bytes belong here, NOT in the low-occupancy scan;
// round-6 fusion A/B proved this at +11 us). Blocks 0..3 also init out=b_out.
// ---------------------------------------------------------------------------
__global__ __launch_bounds__(256) void reduce_part(float* __restrict__ part,
                                                   const float* __restrict__ b_in,
                                                   const float* __restrict__ b_out,
                                                   float* __restrict__ out,
                                                   int nsplit) {
    const int idx = blockIdx.x * 256 + threadIdx.x;  // float4 idx over T*H/4
    const int h4 = idx & (H / 4 - 1);
    float4 s = ((const float4*)b_in)[h4];
    const int plane4 = T * H / 4;
    for (int sp = 0; sp < nsplit; ++sp) {
        float4 v = ((const float4*)part)[(size_t)sp * plane4 + idx];
        s.x += v.x; s.y += v.y; s.z += v.z; s.w += v.w;
    }
    ((float4*)part)[idx] = s;
    if (blockIdx.x < O / 256) {
        const int o = blockIdx.x * 256 + threadIdx.x;
        out[o] = b_out[o];
    }
}

// ---------------------------------------------------------------------------
// Kernel 5: LIF scan over T. One thread per h (hard parallelism cap H=4096).
// 32-deep load batches double-buffered: batch b+1's 32 loads are in flight
// during batch b's dependent LIF chain. Reads one 4 MB plane (L2/L3-warm).
// ---------------------------------------------------------------------------
__global__ __launch_bounds__(64) void lif_scan(const float* __restrict__ cur, // [T,H]
                                               const float* __restrict__ m0v, // [H]
                                               float* __restrict__ agg) {     // [H]
    const int h = blockIdx.x * 64 + threadIdx.x;
    float m = m0v[h];
    float cnt = 0.f;
    float buf[2][32];
#pragma unroll
    for (int j = 0; j < 32; ++j) buf[0][j] = cur[(size_t)j * H + h];
#pragma unroll
    for (int b = 0; b < 8; ++b) {
        if (b + 1 < 8) {
#pragma unroll
            for (int j = 0; j < 32; ++j)
                buf[(b + 1) & 1][j] = cur[(size_t)((b + 1) * 32 + j) * H + h];
        }
#pragma unroll
        for (int j = 0; j < 32; ++j) {
            m = DECAY * m + buf[b & 1][j];
            if (m > THRESH) { cnt += 1.f; m = 0.f; }
        }
    }
    agg[h] = cnt * (1.0f / (float)T);
}

// ---------------------------------------------------------------------------
// Kernel 6 (fallback only): out[o] = b_out[o]
// ---------------------------------------------------------------------------
__global__ __launch_bounds__(256) void out_init(const float* __restrict__ b_out,
                                                float* __restrict__ out) {
    const int o = blockIdx.x * 256 + threadIdx.x;
    out[o] = b_out[o];
}

// ---------------------------------------------------------------------------
// Kernel 7: out += agg @ W_out  (out pre-set to b_out)
// ---------------------------------------------------------------------------
__global__ __launch_bounds__(256) void out_gemv(const float* __restrict__ agg,
                                                const float* __restrict__ Wout,  // [H,O]
                                                float* __restrict__ out) {
    const int o = blockIdx.x * 256 + threadIdx.x;
    const int h0 = blockIdx.y * 64;
    float s = 0.f;
#pragma unroll 8
    for (int hh = h0; hh < h0 + 64; ++hh) {
        s += agg[hh] * Wout[(size_t)hh * O + o];
    }
    atomicAdd(&out[o], s);
}

// ---------------------------------------------------------------------------
extern "C" void kernel_launch(void* const* d_in, const int* in_sizes, int n_in,
                              void* d_out, int out_size, void* d_ws, size_t ws_size,
                              hipStream_t stream) {
    const float* x     = (const float*)d_in[0];
    const float* W_in  = (const float*)d_in[1];
    const float* b_in  = (const float*)d_in[2];
    const float* W_out = (const float*)d_in[3];
    const float* b_out = (const float*)d_in[4];
    const float* m0    = (const float*)d_in[5];
    float* out = (float*)d_out;

    // ws: xbar_hi [T*I u16] | xbar_lo [T*I u16] | agg [H f32] | part [KSPLIT*T*H f32]
    unsigned short* xh = (unsigned short*)d_ws;
    unsigned short* xl = xh + (size_t)T * I;
    float* agg  = (float*)(xl + (size_t)T * I);
    float* part = agg + H;

    const size_t need = (size_t)2 * T * I * 2 + (size_t)H * 4 + (size_t)KSPLIT * T * H * 4;
    const int fits = (ws_size >= need) ? 1 : 0;  // ws_size constant -> same path every launch

    // 1) batch mean -> bf16 hi/lo planes
    batch_reduce<<<(T * I / 4) / 256, 256, 0, stream>>>(x, xh, xl);

    dim3 g2(H / BN, KSPLIT);
    if (fits) {
        // 2) MFMA GEMM into split-K partial planes (plain stores)
        gemm_in<<<g2, 256, 0, stream>>>(xh, xl, W_in, part, 0);
        // 3) fold partials + bias into plane 0 (+ out = b_out init)
        reduce_part<<<(T * H / 4) / 256, 256, 0, stream>>>(part, b_in, b_out, out, KSPLIT);
    } else {
        // fallback (small ws): atomic accumulation into a single bias-primed plane
        cur_init<<<(T * H / 4) / 256, 256, 0, stream>>>(b_in, part);
        gemm_in<<<g2, 256, 0, stream>>>(xh, xl, W_in, part, 1);
        out_init<<<O / 256, 256, 0, stream>>>(b_out, out);
    }

    // 4) LIF scan over T -> agg[h]
    lif_scan<<<H / 64, 64, 0, stream>>>(part, m0, agg);

    // 5) out += agg @ W_out
    dim3 g4(O / 256, H / 64);
    out_gemv<<<g4, 256, 0, stream>>>(agg, W_out, out);
}